// Round 5
// baseline (1145.131 us; speedup 1.0000x reference)
//
#include <hip/hip_runtime.h>
#include <cmath>

typedef __attribute__((ext_vector_type(8))) _Float16 f16x8;
typedef __attribute__((ext_vector_type(8))) unsigned short u16x8;
typedef __attribute__((ext_vector_type(4))) float f32x4;

__device__ __forceinline__ unsigned short f2h(float f) {
  return __builtin_bit_cast(unsigned short, (_Float16)f);
}
__device__ __forceinline__ float h2f(unsigned short u) {
  return (float)__builtin_bit_cast(_Float16, u);
}

__device__ __forceinline__ void async16(const void* gp, void* lp) {
  __builtin_amdgcn_global_load_lds(
      (const __attribute__((address_space(1))) void*)gp,
      (__attribute__((address_space(3))) void*)lp, 16, 0, 0);
}

// ---------------- fused weight transpose + cast (all 6 weights, 1 launch) ----
// W (K x N) f32 -> WT (N x K) f16, matrix selected by blockIdx.z.
struct TCArgs {
  const float* W[6];
  unsigned short* T[6];
  int K[6];
  int N[6];
};

__global__ __launch_bounds__(256) void transpose_cast6(TCArgs a) {
  const int z = blockIdx.z;
  const int K = a.K[z], N = a.N[z];
  const int n0 = blockIdx.x * 32, k0 = blockIdx.y * 32;
  if (n0 >= N || k0 >= K) return;
  const float* __restrict__ W = a.W[z];
  unsigned short* __restrict__ WT = a.T[z];
  __shared__ float tile[32][33];
  const int tx = threadIdx.x & 31, ty = threadIdx.x >> 5;
#pragma unroll
  for (int r = 0; r < 4; ++r)
    tile[ty + 8 * r][tx] = W[(size_t)(k0 + ty + 8 * r) * N + n0 + tx];
  __syncthreads();
#pragma unroll
  for (int r = 0; r < 4; ++r)
    WT[(size_t)(n0 + ty + 8 * r) * K + k0 + tx] = f2h(tile[tx][ty + 8 * r]);
}

// ---------------- layernorm (C=1024) f32 -> f16 ------------------------------
__global__ __launch_bounds__(256) void layernorm_cast(
    const float* __restrict__ x, const float* __restrict__ g,
    const float* __restrict__ bt, unsigned short* __restrict__ out) {
  const int row = blockIdx.x, tid = threadIdx.x;
  const float4 v = ((const float4*)(x + (size_t)row * 1024))[tid];
  float s = v.x + v.y + v.z + v.w;
  float ss = v.x * v.x + v.y * v.y + v.z * v.z + v.w * v.w;
#pragma unroll
  for (int off = 32; off >= 1; off >>= 1) {
    s += __shfl_down(s, off);
    ss += __shfl_down(ss, off);
  }
  __shared__ float red[10];
  const int wave = tid >> 6, lane = tid & 63;
  if (lane == 0) { red[wave] = s; red[4 + wave] = ss; }
  __syncthreads();
  if (tid == 0) {
    float S = red[0] + red[1] + red[2] + red[3];
    float SS = red[4] + red[5] + red[6] + red[7];
    float mu = S * (1.f / 1024.f);
    float var = SS * (1.f / 1024.f) - mu * mu;
    red[8] = mu;
    red[9] = rsqrtf(var + 1e-5f);
  }
  __syncthreads();
  const float mu = red[8], rs = red[9];
  const float4 gv = ((const float4*)g)[tid];
  const float4 bv = ((const float4*)bt)[tid];
  ushort4 r;
  r.x = f2h((v.x - mu) * rs * gv.x + bv.x);
  r.y = f2h((v.y - mu) * rs * gv.y + bv.y);
  r.z = f2h((v.z - mu) * rs * gv.z + bv.z);
  r.w = f2h((v.w - mu) * rs * gv.w + bv.w);
  ((ushort4*)(out + (size_t)row * 1024))[tid] = r;
}

// ---------------- fused residual + layernorm --------------------------------
__global__ __launch_bounds__(256) void resid_ln(
    const float* __restrict__ x, const unsigned short* __restrict__ pr,
    const float* __restrict__ pb, const float* __restrict__ g,
    const float* __restrict__ bt, float* __restrict__ out,
    unsigned short* __restrict__ h2) {
  const int row = blockIdx.x, tid = threadIdx.x;
  const size_t off = (size_t)row * 1024;
  const float4 xv = ((const float4*)(x + off))[tid];
  const ushort4 pv = ((const ushort4*)(pr + off))[tid];
  const float4 bb = ((const float4*)pb)[tid];
  float4 v;
  v.x = xv.x + h2f(pv.x) + bb.x;
  v.y = xv.y + h2f(pv.y) + bb.y;
  v.z = xv.z + h2f(pv.z) + bb.z;
  v.w = xv.w + h2f(pv.w) + bb.w;
  ((float4*)(out + off))[tid] = v;
  float s = v.x + v.y + v.z + v.w;
  float ss = v.x * v.x + v.y * v.y + v.z * v.z + v.w * v.w;
#pragma unroll
  for (int o = 32; o >= 1; o >>= 1) {
    s += __shfl_down(s, o);
    ss += __shfl_down(ss, o);
  }
  __shared__ float red[10];
  const int wave = tid >> 6, lane = tid & 63;
  if (lane == 0) { red[wave] = s; red[4 + wave] = ss; }
  __syncthreads();
  if (tid == 0) {
    float S = red[0] + red[1] + red[2] + red[3];
    float SS = red[4] + red[5] + red[6] + red[7];
    float mu = S * (1.f / 1024.f);
    float var = SS * (1.f / 1024.f) - mu * mu;
    red[8] = mu;
    red[9] = rsqrtf(var + 1e-5f);
  }
  __syncthreads();
  const float mu = red[8], rs = red[9];
  const float4 gv = ((const float4*)g)[tid];
  const float4 bv = ((const float4*)bt)[tid];
  ushort4 r;
  r.x = f2h((v.x - mu) * rs * gv.x + bv.x);
  r.y = f2h((v.y - mu) * rs * gv.y + bv.y);
  r.z = f2h((v.z - mu) * rs * gv.z + bv.z);
  r.w = f2h((v.w - mu) * rs * gv.w + bv.w);
  ((ushort4*)(h2 + off))[tid] = r;
}

// ---------------- final residual add: out += y + b ---------------------------
__global__ __launch_bounds__(256) void resid_add(
    float* __restrict__ out, const unsigned short* __restrict__ y,
    const float* __restrict__ b) {
  const int row = blockIdx.x, tid = threadIdx.x;
  const size_t off = (size_t)row * 1024;
  float4 o = ((const float4*)(out + off))[tid];
  const ushort4 yv = ((const ushort4*)(y + off))[tid];
  const float4 bv = ((const float4*)b)[tid];
  o.x += h2f(yv.x) + bv.x;
  o.y += h2f(yv.y) + bv.y;
  o.z += h2f(yv.z) + bv.z;
  o.w += h2f(yv.w) + bv.w;
  ((float4*)(out + off))[tid] = o;
}

// ---------------- f16 GEMM, 256x256 tile, BK=64, 8-phase counted-vmcnt -------
// All four GEMMs. C = A (MxK) * BT^T (BT NxK). 512 threads = 8 waves (2M x 4N),
// per-wave 128x64 output. LDS 128 KiB: 2 dbuf x (A 256x64 + B 256x64) f16.
// Per K-tile: 4 phases {ds_read; stage 1 half (2 loads); barrier; lgkmcnt(0);
// setprio(1); 16 MFMA; setprio(0); barrier}; vmcnt(6) once per tile boundary.
// Counter status (r4): VGPR=128 no-spill, bank-conflicts=0, FETCH halved vs
// 128^2, MfmaUtil 37% (8-phase overlap not established — m232-class null).

#define STAGE_A(TT, KKH)                                                       \
  {                                                                            \
    unsigned short* d = smem + ((TT) & 1) * 32768 + (KKH) * 8192 + wave * 512; \
    const unsigned short* sp_ = pA + (size_t)(TT) * 64 + (KKH) * 32;           \
    async16(sp_, d);                                                           \
    async16(sp_ + rstep, d + 4096);                                            \
  }

#define STAGE_B(TT, KKH)                                                       \
  {                                                                            \
    unsigned short* d =                                                        \
        smem + ((TT) & 1) * 32768 + 16384 + (KKH) * 8192 + wave * 512;         \
    const unsigned short* sp_ = pB + (size_t)(TT) * 64 + (KKH) * 32;           \
    async16(sp_, d);                                                           \
    async16(sp_ + rstep, d + 4096);                                            \
  }

#define GPHASE(KK, MH, STAGE, TAILW)                                           \
  {                                                                            \
    f16x8 af[4];                                                               \
    _Pragma("unroll") for (int i = 0; i < 4; ++i) {                            \
      const int ra = wm * 128 + ((MH)*4 + i) * 16 + l16;                       \
      af[i] = __builtin_bit_cast(                                              \
          f16x8, *(const u16x8*)&bufA[(KK)*8192 + ra * 32 +                    \
                                      ((g16 ^ ((ra >> 1) & 3)) * 8)]);         \
    }                                                                          \
    if ((MH) == 0) {                                                           \
      _Pragma("unroll") for (int j = 0; j < 4; ++j) {                          \
        const int rb = wn * 64 + j * 16 + l16;                                 \
        bf[j] = __builtin_bit_cast(                                            \
            f16x8, *(const u16x8*)&bufB[(KK)*8192 + rb * 32 +                  \
                                        ((g16 ^ ((rb >> 1) & 3)) * 8)]);       \
      }                                                                        \
    }                                                                          \
    STAGE;                                                                     \
    __builtin_amdgcn_s_barrier();                                              \
    asm volatile("s_waitcnt lgkmcnt(0)" ::: "memory");                         \
    __builtin_amdgcn_s_setprio(1);                                             \
    _Pragma("unroll") for (int i = 0; i < 4; ++i)                              \
        _Pragma("unroll") for (int j = 0; j < 4; ++j) acc[(MH)*4 + i][j] =     \
        __builtin_amdgcn_mfma_f32_16x16x32_f16(af[i], bf[j],                   \
                                               acc[(MH)*4 + i][j], 0, 0, 0);   \
    __builtin_amdgcn_s_setprio(0);                                             \
    TAILW;                                                                     \
    __builtin_amdgcn_s_barrier();                                              \
  }

__global__ __launch_bounds__(512) void gemm256(
    const unsigned short* __restrict__ A, const unsigned short* __restrict__ BT,
    int M, int N, int K,
    const float* __restrict__ bias, unsigned short* __restrict__ outB, int gelu) {
  __shared__ __align__(16) unsigned short smem[65536];  // 128 KiB
  const int tid = threadIdx.x, wave = tid >> 6, lane = tid & 63;
  const int l16 = lane & 15, g16 = lane >> 4;
  const int wm = wave >> 2, wn = wave & 3;

  // XCD-aware remap (bijective: gy=128 divisible by 8)
  const int lin = blockIdx.y * gridDim.x + blockIdx.x;
  const int t_ = lin >> 3;
  const int bx = t_ % gridDim.x;
  const int by = (lin & 7) + 8 * (t_ / gridDim.x);
  const int row0 = by * 256, col0 = bx * 256;

  const int r_ = tid >> 2;                               // 0..127
  const int s_ = ((tid & 3) ^ ((tid >> 3) & 3)) * 8;     // XOR segment swizzle
  const unsigned short* pA = A + (size_t)(row0 + r_) * K + s_;
  const unsigned short* pB = BT + (size_t)(col0 + r_) * K + s_;
  const size_t rstep = (size_t)128 * K;
  const int NT = K >> 6;

  f32x4 acc[8][4] = {};

  // ---- prologue: 7 halves (tile0 complete + 3 halves of tile1) --------------
  STAGE_B(0, 0);
  STAGE_A(0, 0);
  STAGE_B(0, 1);
  STAGE_A(0, 1);
  STAGE_B(1, 0);
  STAGE_A(1, 0);
  STAGE_B(1, 1);
  asm volatile("s_waitcnt vmcnt(6)" ::: "memory");
  __builtin_amdgcn_s_barrier();

  // ---- main loop: tiles 0 .. NT-3 -------------------------------------------
  for (int t = 0; t < NT - 2; ++t) {
    const unsigned short* bufA = smem + (t & 1) * 32768;
    const unsigned short* bufB = bufA + 16384;
    f16x8 bf[4];
    GPHASE(0, 0, STAGE_A(t + 1, 1), )
    GPHASE(0, 1, STAGE_B(t + 2, 0), )
    GPHASE(1, 0, STAGE_A(t + 2, 0), )
    GPHASE(1, 1, STAGE_B(t + 2, 1),
           asm volatile("s_waitcnt vmcnt(6)" ::: "memory"))
  }

  // ---- tail tile NT-2: stage last half of NT-1, then drain ------------------
  {
    const int t = NT - 2;
    const unsigned short* bufA = smem + (t & 1) * 32768;
    const unsigned short* bufB = bufA + 16384;
    f16x8 bf[4];
    GPHASE(0, 0, STAGE_A(t + 1, 1), )
    GPHASE(0, 1, , )
    GPHASE(1, 0, , )
    GPHASE(1, 1, , asm volatile("s_waitcnt vmcnt(0)" ::: "memory"))
  }
  // ---- tail tile NT-1: pure compute -----------------------------------------
  {
    const int t = NT - 1;
    const unsigned short* bufA = smem + (t & 1) * 32768;
    const unsigned short* bufB = bufA + 16384;
    f16x8 bf[4];
    GPHASE(0, 0, , )
    GPHASE(0, 1, , )
    GPHASE(1, 0, , )
    GPHASE(1, 1, , )
  }

  // ---- epilogue: acc -> f16 via wave-private LDS (stride 68), 16B stores ----
  unsigned short* scr = smem + wave * 4352;  // 64 x 68 f16 per wave
#pragma unroll
  for (int mh = 0; mh < 2; ++mh) {
#pragma unroll
    for (int j = 0; j < 4; ++j) {
      const float bcol = gelu ? bias[col0 + wn * 64 + j * 16 + l16] : 0.f;
#pragma unroll
      for (int i = 0; i < 4; ++i)
#pragma unroll
        for (int r = 0; r < 4; ++r) {
          float val = acc[mh * 4 + i][j][r] + bcol;
          if (gelu) val = 0.5f * val * (1.0f + erff(val * 0.70710678118f));
          scr[(i * 16 + g16 * 4 + r) * 68 + j * 16 + l16] = f2h(val);
        }
    }
#pragma unroll
    for (int rr = 0; rr < 8; ++rr) {
      const int lr = rr * 8 + (lane >> 3);
      const int lc = (lane & 7) * 8;
      const u16x8 val = *(const u16x8*)&scr[lr * 68 + lc];
      *(u16x8*)(outB + (size_t)(row0 + wm * 128 + mh * 64 + lr) * N + col0 +
                wn * 64 + lc) = val;
    }
  }
}

// ---------------- attention stage 1: partial S = Q^T K over an n-chunk -------
__global__ __launch_bounds__(256) void attn_qk_part(
    const unsigned short* __restrict__ qkv, float* __restrict__ sp) {
  constexpr int ST = 72;
  __shared__ unsigned short sQT[64 * ST];  // [dd][n]
  __shared__ unsigned short sKT[64 * ST];  // [e][n]
  const int bx = blockIdx.x, bh = bx >> 2, chunk = bx & 3;
  const int b = bh >> 4, h = bh & 15;
  const size_t base = (size_t)b * 4096 * 3072 + (size_t)h * 64;
  const int tid = threadIdx.x, wave = tid >> 6, lane = tid & 63;
  const int l16 = lane & 15, g16 = lane >> 4;
  const int wm = wave & 1, wn = wave >> 1;
  const int srow = tid >> 2, sseg = tid & 3;

  f32x4 acc[2][2] = {};

  for (int ntl = 0; ntl < 16; ++ntl) {
    const int nt = chunk * 16 + ntl;
    __syncthreads();
    const size_t roff = base + (size_t)(nt * 64 + srow) * 3072 + sseg * 16;
    const u16x8 q0 = *(const u16x8*)(qkv + roff);
    const u16x8 q1 = *(const u16x8*)(qkv + roff + 8);
    const u16x8 k0 = *(const u16x8*)(qkv + roff + 1024);
    const u16x8 k1 = *(const u16x8*)(qkv + roff + 1032);
#pragma unroll
    for (int ii = 0; ii < 8; ++ii) {
      sQT[(sseg * 16 + ii) * ST + srow] = q0[ii];
      sQT[(sseg * 16 + 8 + ii) * ST + srow] = q1[ii];
      sKT[(sseg * 16 + ii) * ST + srow] = k0[ii];
      sKT[(sseg * 16 + 8 + ii) * ST + srow] = k1[ii];
    }
    __syncthreads();
#pragma unroll
    for (int kk = 0; kk < 2; ++kk) {
      f16x8 aq[2], bk[2];
#pragma unroll
      for (int i = 0; i < 2; ++i)
        aq[i] = __builtin_bit_cast(f16x8,
            *(const u16x8*)&sQT[(wm * 32 + i * 16 + l16) * ST + kk * 32 + g16 * 8]);
#pragma unroll
      for (int j = 0; j < 2; ++j)
        bk[j] = __builtin_bit_cast(f16x8,
            *(const u16x8*)&sKT[(wn * 32 + j * 16 + l16) * ST + kk * 32 + g16 * 8]);
#pragma unroll
      for (int i = 0; i < 2; ++i)
#pragma unroll
        for (int j = 0; j < 2; ++j)
          acc[i][j] = __builtin_amdgcn_mfma_f32_16x16x32_f16(aq[i], bk[j], acc[i][j], 0, 0, 0);
    }
  }

  float* o = sp + (size_t)bx * 4096;
#pragma unroll
  for (int i = 0; i < 2; ++i)
#pragma unroll
    for (int j = 0; j < 2; ++j)
#pragma unroll
      for (int r = 0; r < 4; ++r)
        o[(wm * 32 + i * 16 + g16 * 4 + r) * 64 + (wn * 32 + j * 16 + l16)] = acc[i][j][r];
}

// ---------------- attention stage 2: chunk-reduce + softmax -> Am (f16) ------
// Wave-per-row: 2048 blocks x 256 threads; wave w of block handles row
// gid = bid*4+w -> (bh, dd); lane = e. Coalesced 256B chunk loads, shfl
// max/sum reduce. Replaces the 128x64 serial version (half-idle GPU,
// 256B-stride uncoalesced accesses).
__global__ __launch_bounds__(256) void attn_softmax(
    const float* __restrict__ sp, unsigned short* __restrict__ am) {
  const int gid = blockIdx.x * 4 + (threadIdx.x >> 6);  // 0..8191
  const int lane = threadIdx.x & 63;
  const int bh = gid >> 6, dd = gid & 63;
  const float* p = sp + (size_t)bh * 16384 + dd * 64 + lane;
  const float v = p[0] + p[4096] + p[8192] + p[12288];
  float mx = v;
#pragma unroll
  for (int o = 32; o >= 1; o >>= 1) mx = fmaxf(mx, __shfl_xor(mx, o));
  const float e = __expf(0.125f * (v - mx));
  float s = e;
#pragma unroll
  for (int o = 32; o >= 1; o >>= 1) s += __shfl_xor(s, o);
  am[(size_t)bh * 4096 + dd * 64 + lane] = f2h(e / s);
}

// ---------------- attention stage 3: O = A * V over an n-chunk ---------------
// scrambled output: o[b*4096 + dd*64 + h*4 + (n>>10)][n & 1023]
__global__ __launch_bounds__(256) void attn_pv(
    const unsigned short* __restrict__ qkv, const unsigned short* __restrict__ am,
    unsigned short* __restrict__ o) {
  const int bx = blockIdx.x, bh = bx >> 2, chunk = bx & 3;
  const int b = bh >> 4, h = bh & 15;
  const size_t base = (size_t)b * 4096 * 3072 + (size_t)h * 64;
  const int tid = threadIdx.x, wave = tid >> 6, lane = tid & 63;
  const int l16 = lane & 15, g16 = lane >> 4;
  const int wm = wave & 1, wn = wave >> 1;

  f16x8 amf[2][2];
#pragma unroll
  for (int i = 0; i < 2; ++i)
#pragma unroll
    for (int kk = 0; kk < 2; ++kk)
      amf[i][kk] = __builtin_bit_cast(f16x8,
          *(const u16x8*)(am + (size_t)bh * 4096 +
                          (wm * 32 + i * 16 + l16) * 64 + kk * 32 + g16 * 8));

  for (int ntl = 0; ntl < 16; ++ntl) {
    const int nt = chunk * 16 + ntl;
    f32x4 oc[2][2] = {};
#pragma unroll
    for (int kk = 0; kk < 2; ++kk) {
#pragma unroll
      for (int j = 0; j < 2; ++j) {
        const f16x8 vf = __builtin_bit_cast(f16x8,
            *(const u16x8*)(qkv + base + 2048 +
                            (size_t)(nt * 64 + wn * 32 + j * 16 + l16) * 3072 +
                            kk * 32 + g16 * 8));
#pragma unroll
        for (int i = 0; i < 2; ++i)
          oc[i][j] = __builtin_amdgcn_mfma_f32_16x16x32_f16(amf[i][kk], vf, oc[i][j], 0, 0, 0);
      }
    }
#pragma unroll
    for (int i = 0; i < 2; ++i)
#pragma unroll
      for (int j = 0; j < 2; ++j)
#pragma unroll
        for (int r = 0; r < 4; ++r) {
          const int dd = wm * 32 + i * 16 + g16 * 4 + r;
          const int nf = nt * 64 + wn * 32 + j * 16 + l16;
          const int row = b * 4096 + dd * 64 + h * 4 + (nf >> 10);
          o[(size_t)row * 1024 + (nf & 1023)] = f2h(oc[i][j][r]);
        }
  }
}

// -----------------------------------------------------------------------------
extern "C" void kernel_launch(void* const* d_in, const int* in_sizes, int n_in,
                              void* d_out, int out_size, void* d_ws, size_t ws_size,
                              hipStream_t stream) {
  (void)in_sizes; (void)n_in; (void)out_size; (void)ws_size;
  const float* x = (const float*)d_in[0];
  const float* ln1g = (const float*)d_in[1];
  const float* ln1b = (const float*)d_in[2];
  const float* ln2g = (const float*)d_in[3];
  const float* ln2b = (const float*)d_in[4];
  const float* wq = (const float*)d_in[5];
  const float* wk = (const float*)d_in[6];
  const float* wv = (const float*)d_in[7];
  const float* projw = (const float*)d_in[8];
  const float* projb = (const float*)d_in[9];
  const float* fc1w = (const float*)d_in[10];
  const float* fc1b = (const float*)d_in[11];
  const float* fc2w = (const float*)d_in[12];
  const float* fc2b = (const float*)d_in[13];
  float* out = (float*)d_out;

  const int M = 8 * 4096, C = 1024, HF = 2048;
  const size_t MC = (size_t)M * C;

  unsigned short* p = (unsigned short*)d_ws;
  unsigned short* wqkvT = p; p += (size_t)3 * C * C;  // [3072 x 1024]
  unsigned short* prT = p; p += (size_t)C * C;
  unsigned short* f1T = p; p += (size_t)HF * C;
  unsigned short* f2T = p; p += (size_t)C * HF;
  unsigned short* hb = p;  p += MC;          // region RA (64 MB)
  unsigned short* qkvb = p; p += 3 * MC;     // region RB (192 MB)
  // Aliases (lifetimes are strictly stream-ordered):
  float* Spart = (float*)hb;                 // attn scratch (8 MB), hb dead after qkv GEMM
  unsigned short* Am = wqkvT;                // 1 MB, wqkvT dead after qkv GEMM
  unsigned short* ob = hb;                   // attn output, clobbers consumed Spart
  unsigned short* projout = qkvb;            // RB[0,MC): qkvb dead after attn_pv
  unsigned short* h2 = qkvb + 2 * MC;        // RB[2MC,3MC)
  unsigned short* h3 = qkvb;                 // RB[0,2MC): projout dead after resid_ln
  unsigned short* yb = hb;                   // fc2 raw out, ob dead after proj GEMM

  TCArgs ta;
  ta.W[0] = wq;    ta.T[0] = wqkvT;                     ta.K[0] = C;  ta.N[0] = C;
  ta.W[1] = wk;    ta.T[1] = wqkvT + (size_t)C * C;     ta.K[1] = C;  ta.N[1] = C;
  ta.W[2] = wv;    ta.T[2] = wqkvT + (size_t)2 * C * C; ta.K[2] = C;  ta.N[2] = C;
  ta.W[3] = projw; ta.T[3] = prT;                       ta.K[3] = C;  ta.N[3] = C;
  ta.W[4] = fc1w;  ta.T[4] = f1T;                       ta.K[4] = C;  ta.N[4] = HF;
  ta.W[5] = fc2w;  ta.T[5] = f2T;                       ta.K[5] = HF; ta.N[5] = C;
  transpose_cast6<<<dim3(HF / 32, HF / 32, 6), 256, 0, stream>>>(ta);

  layernorm_cast<<<M, 256, 0, stream>>>(x, ln1g, ln1b, hb);

  gemm256<<<dim3(3 * C / 256, M / 256), 512, 0, stream>>>(
      hb, wqkvT, M, 3 * C, C, nullptr, qkvb, 0);

  attn_qk_part<<<512, 256, 0, stream>>>(qkvb, Spart);
  attn_softmax<<<2048, 256, 0, stream>>>(Spart, Am);
  attn_pv<<<512, 256, 0, stream>>>(qkvb, Am, ob);

  gemm256<<<dim3(C / 256, M / 256), 512, 0, stream>>>(
      ob, prT, M, C, C, nullptr, projout, 0);

  resid_ln<<<M, 256, 0, stream>>>(x, projout, projb, ln2g, ln2b, out, h2);

  gemm256<<<dim3(HF / 256, M / 256), 512, 0, stream>>>(
      h2, f1T, M, HF, C, fc1b, h3, 1);

  gemm256<<<dim3(C / 256, M / 256), 512, 0, stream>>>(
      h3, f2T, M, C, HF, nullptr, yb, 0);

  resid_add<<<M, 256, 0, stream>>>(out, yb, fc2b);
}

// Round 6
// 1095.729 us; speedup vs baseline: 1.0451x; 1.0451x over previous
//
#include <hip/hip_runtime.h>
#include <cmath>

typedef __attribute__((ext_vector_type(8))) _Float16 f16x8;
typedef __attribute__((ext_vector_type(8))) unsigned short u16x8;
typedef __attribute__((ext_vector_type(4))) float f32x4;

__device__ __forceinline__ unsigned short f2h(float f) {
  return __builtin_bit_cast(unsigned short, (_Float16)f);
}
__device__ __forceinline__ float h2f(unsigned short u) {
  return (float)__builtin_bit_cast(_Float16, u);
}

__device__ __forceinline__ void async16(const void* gp, void* lp) {
  __builtin_amdgcn_global_load_lds(
      (const __attribute__((address_space(1))) void*)gp,
      (__attribute__((address_space(3))) void*)lp, 16, 0, 0);
}

// ---------------- fused weight transpose + cast (all 6 weights, 1 launch) ----
struct TCArgs {
  const float* W[6];
  unsigned short* T[6];
  int K[6];
  int N[6];
};

__global__ __launch_bounds__(256) void transpose_cast6(TCArgs a) {
  const int z = blockIdx.z;
  const int K = a.K[z], N = a.N[z];
  const int n0 = blockIdx.x * 32, k0 = blockIdx.y * 32;
  if (n0 >= N || k0 >= K) return;
  const float* __restrict__ W = a.W[z];
  unsigned short* __restrict__ WT = a.T[z];
  __shared__ float tile[32][33];
  const int tx = threadIdx.x & 31, ty = threadIdx.x >> 5;
#pragma unroll
  for (int r = 0; r < 4; ++r)
    tile[ty + 8 * r][tx] = W[(size_t)(k0 + ty + 8 * r) * N + n0 + tx];
  __syncthreads();
#pragma unroll
  for (int r = 0; r < 4; ++r)
    WT[(size_t)(n0 + ty + 8 * r) * K + k0 + tx] = f2h(tile[tx][ty + 8 * r]);
}

// ---------------- layernorm (C=1024) f32 -> f16 ------------------------------
__global__ __launch_bounds__(256) void layernorm_cast(
    const float* __restrict__ x, const float* __restrict__ g,
    const float* __restrict__ bt, unsigned short* __restrict__ out) {
  const int row = blockIdx.x, tid = threadIdx.x;
  const float4 v = ((const float4*)(x + (size_t)row * 1024))[tid];
  float s = v.x + v.y + v.z + v.w;
  float ss = v.x * v.x + v.y * v.y + v.z * v.z + v.w * v.w;
#pragma unroll
  for (int off = 32; off >= 1; off >>= 1) {
    s += __shfl_down(s, off);
    ss += __shfl_down(ss, off);
  }
  __shared__ float red[10];
  const int wave = tid >> 6, lane = tid & 63;
  if (lane == 0) { red[wave] = s; red[4 + wave] = ss; }
  __syncthreads();
  if (tid == 0) {
    float S = red[0] + red[1] + red[2] + red[3];
    float SS = red[4] + red[5] + red[6] + red[7];
    float mu = S * (1.f / 1024.f);
    float var = SS * (1.f / 1024.f) - mu * mu;
    red[8] = mu;
    red[9] = rsqrtf(var + 1e-5f);
  }
  __syncthreads();
  const float mu = red[8], rs = red[9];
  const float4 gv = ((const float4*)g)[tid];
  const float4 bv = ((const float4*)bt)[tid];
  ushort4 r;
  r.x = f2h((v.x - mu) * rs * gv.x + bv.x);
  r.y = f2h((v.y - mu) * rs * gv.y + bv.y);
  r.z = f2h((v.z - mu) * rs * gv.z + bv.z);
  r.w = f2h((v.w - mu) * rs * gv.w + bv.w);
  ((ushort4*)(out + (size_t)row * 1024))[tid] = r;
}

// ---------------- fused residual + layernorm --------------------------------
__global__ __launch_bounds__(256) void resid_ln(
    const float* __restrict__ x, const unsigned short* __restrict__ pr,
    const float* __restrict__ pb, const float* __restrict__ g,
    const float* __restrict__ bt, float* __restrict__ out,
    unsigned short* __restrict__ h2) {
  const int row = blockIdx.x, tid = threadIdx.x;
  const size_t off = (size_t)row * 1024;
  const float4 xv = ((const float4*)(x + off))[tid];
  const ushort4 pv = ((const ushort4*)(pr + off))[tid];
  const float4 bb = ((const float4*)pb)[tid];
  float4 v;
  v.x = xv.x + h2f(pv.x) + bb.x;
  v.y = xv.y + h2f(pv.y) + bb.y;
  v.z = xv.z + h2f(pv.z) + bb.z;
  v.w = xv.w + h2f(pv.w) + bb.w;
  ((float4*)(out + off))[tid] = v;
  float s = v.x + v.y + v.z + v.w;
  float ss = v.x * v.x + v.y * v.y + v.z * v.z + v.w * v.w;
#pragma unroll
  for (int o = 32; o >= 1; o >>= 1) {
    s += __shfl_down(s, o);
    ss += __shfl_down(ss, o);
  }
  __shared__ float red[10];
  const int wave = tid >> 6, lane = tid & 63;
  if (lane == 0) { red[wave] = s; red[4 + wave] = ss; }
  __syncthreads();
  if (tid == 0) {
    float S = red[0] + red[1] + red[2] + red[3];
    float SS = red[4] + red[5] + red[6] + red[7];
    float mu = S * (1.f / 1024.f);
    float var = SS * (1.f / 1024.f) - mu * mu;
    red[8] = mu;
    red[9] = rsqrtf(var + 1e-5f);
  }
  __syncthreads();
  const float mu = red[8], rs = red[9];
  const float4 gv = ((const float4*)g)[tid];
  const float4 bv = ((const float4*)bt)[tid];
  ushort4 r;
  r.x = f2h((v.x - mu) * rs * gv.x + bv.x);
  r.y = f2h((v.y - mu) * rs * gv.y + bv.y);
  r.z = f2h((v.z - mu) * rs * gv.z + bv.z);
  r.w = f2h((v.w - mu) * rs * gv.w + bv.w);
  ((ushort4*)(h2 + off))[tid] = r;
}

// ---------------- f16 GEMM, 256x256 tile, BK=64, 8-phase counted-vmcnt -------
// 512 threads = 8 waves (2M x 4N), per-wave 128x64 out. LDS 128 KiB dbuf.
// r5 post-mortem: MfmaUtil 37% (serial ds_read->MFMA per phase, ~6200cyc/Ktile
// vs m201's 3300). Theory: raw s_barrier is NOT a fence -> compiler re-sinks
// the C++ ds_reads/stages, destroying the phase interleave. Fix: pin the
// skeleton with sched_barrier(0) at phase boundaries (MFMA cluster internals
// left free per m141).
// Optional fused residual epilogue (resid!=nullptr): out += h2f(f2h(acc))+rbias
// (bit-identical to old separate resid_add).

#define STAGE_A(TT, KKH)                                                       \
  {                                                                            \
    unsigned short* d = smem + ((TT) & 1) * 32768 + (KKH) * 8192 + wave * 512; \
    const unsigned short* sp_ = pA + (size_t)(TT) * 64 + (KKH) * 32;           \
    async16(sp_, d);                                                           \
    async16(sp_ + rstep, d + 4096);                                            \
  }

#define STAGE_B(TT, KKH)                                                       \
  {                                                                            \
    unsigned short* d =                                                        \
        smem + ((TT) & 1) * 32768 + 16384 + (KKH) * 8192 + wave * 512;         \
    const unsigned short* sp_ = pB + (size_t)(TT) * 64 + (KKH) * 32;           \
    async16(sp_, d);                                                           \
    async16(sp_ + rstep, d + 4096);                                            \
  }

#define GPHASE(KK, MH, STAGE, TAILW)                                           \
  {                                                                            \
    f16x8 af[4];                                                               \
    _Pragma("unroll") for (int i = 0; i < 4; ++i) {                            \
      const int ra = wm * 128 + ((MH)*4 + i) * 16 + l16;                       \
      af[i] = __builtin_bit_cast(                                              \
          f16x8, *(const u16x8*)&bufA[(KK)*8192 + ra * 32 +                    \
                                      ((g16 ^ ((ra >> 1) & 3)) * 8)]);         \
    }                                                                          \
    if ((MH) == 0) {                                                           \
      _Pragma("unroll") for (int j = 0; j < 4; ++j) {                          \
        const int rb = wn * 64 + j * 16 + l16;                                 \
        bf[j] = __builtin_bit_cast(                                            \
            f16x8, *(const u16x8*)&bufB[(KK)*8192 + rb * 32 +                  \
                                        ((g16 ^ ((rb >> 1) & 3)) * 8)]);       \
      }                                                                        \
    }                                                                          \
    __builtin_amdgcn_sched_barrier(0);                                         \
    STAGE;                                                                     \
    __builtin_amdgcn_sched_barrier(0);                                         \
    __builtin_amdgcn_s_barrier();                                              \
    asm volatile("s_waitcnt lgkmcnt(0)" ::: "memory");                         \
    __builtin_amdgcn_sched_barrier(0);                                         \
    __builtin_amdgcn_s_setprio(1);                                             \
    _Pragma("unroll") for (int i = 0; i < 4; ++i)                              \
        _Pragma("unroll") for (int j = 0; j < 4; ++j) acc[(MH)*4 + i][j] =     \
        __builtin_amdgcn_mfma_f32_16x16x32_f16(af[i], bf[j],                   \
                                               acc[(MH)*4 + i][j], 0, 0, 0);   \
    __builtin_amdgcn_s_setprio(0);                                             \
    __builtin_amdgcn_sched_barrier(0);                                         \
    TAILW;                                                                     \
    __builtin_amdgcn_s_barrier();                                              \
  }

__global__ __launch_bounds__(512) void gemm256(
    const unsigned short* __restrict__ A, const unsigned short* __restrict__ BT,
    int M, int N, int K,
    const float* __restrict__ bias, unsigned short* __restrict__ outB, int gelu,
    float* __restrict__ resid, const float* __restrict__ rbias) {
  __shared__ __align__(16) unsigned short smem[65536];  // 128 KiB
  const int tid = threadIdx.x, wave = tid >> 6, lane = tid & 63;
  const int l16 = lane & 15, g16 = lane >> 4;
  const int wm = wave >> 2, wn = wave & 3;

  // XCD-aware remap (bijective: gy=128 divisible by 8)
  const int lin = blockIdx.y * gridDim.x + blockIdx.x;
  const int t_ = lin >> 3;
  const int bx = t_ % gridDim.x;
  const int by = (lin & 7) + 8 * (t_ / gridDim.x);
  const int row0 = by * 256, col0 = bx * 256;

  const int r_ = tid >> 2;                               // 0..127
  const int s_ = ((tid & 3) ^ ((tid >> 3) & 3)) * 8;     // XOR segment swizzle
  const unsigned short* pA = A + (size_t)(row0 + r_) * K + s_;
  const unsigned short* pB = BT + (size_t)(col0 + r_) * K + s_;
  const size_t rstep = (size_t)128 * K;
  const int NT = K >> 6;

  f32x4 acc[8][4] = {};

  // ---- prologue: 7 halves (tile0 complete + 3 halves of tile1) --------------
  STAGE_B(0, 0);
  STAGE_A(0, 0);
  STAGE_B(0, 1);
  STAGE_A(0, 1);
  STAGE_B(1, 0);
  STAGE_A(1, 0);
  STAGE_B(1, 1);
  __builtin_amdgcn_sched_barrier(0);
  asm volatile("s_waitcnt vmcnt(6)" ::: "memory");
  __builtin_amdgcn_s_barrier();

  // ---- main loop: tiles 0 .. NT-3 -------------------------------------------
  for (int t = 0; t < NT - 2; ++t) {
    const unsigned short* bufA = smem + (t & 1) * 32768;
    const unsigned short* bufB = bufA + 16384;
    f16x8 bf[4];
    GPHASE(0, 0, STAGE_A(t + 1, 1), )
    GPHASE(0, 1, STAGE_B(t + 2, 0), )
    GPHASE(1, 0, STAGE_A(t + 2, 0), )
    GPHASE(1, 1, STAGE_B(t + 2, 1),
           asm volatile("s_waitcnt vmcnt(6)" ::: "memory"))
  }

  // ---- tail tile NT-2: stage last half of NT-1, then drain ------------------
  {
    const int t = NT - 2;
    const unsigned short* bufA = smem + (t & 1) * 32768;
    const unsigned short* bufB = bufA + 16384;
    f16x8 bf[4];
    GPHASE(0, 0, STAGE_A(t + 1, 1), )
    GPHASE(0, 1, , )
    GPHASE(1, 0, , )
    GPHASE(1, 1, , asm volatile("s_waitcnt vmcnt(0)" ::: "memory"))
  }
  // ---- tail tile NT-1: pure compute -----------------------------------------
  {
    const int t = NT - 1;
    const unsigned short* bufA = smem + (t & 1) * 32768;
    const unsigned short* bufB = bufA + 16384;
    f16x8 bf[4];
    GPHASE(0, 0, , )
    GPHASE(0, 1, , )
    GPHASE(1, 0, , )
    GPHASE(1, 1, , )
  }

  // ---- epilogue: acc -> f16 via wave-private LDS (stride 68), 16B ops -------
  unsigned short* scr = smem + wave * 4352;  // 64 x 68 f16 per wave
#pragma unroll
  for (int mh = 0; mh < 2; ++mh) {
#pragma unroll
    for (int j = 0; j < 4; ++j) {
      const float bcol = gelu ? bias[col0 + wn * 64 + j * 16 + l16] : 0.f;
#pragma unroll
      for (int i = 0; i < 4; ++i)
#pragma unroll
        for (int r = 0; r < 4; ++r) {
          float val = acc[mh * 4 + i][j][r] + bcol;
          if (gelu) val = 0.5f * val * (1.0f + erff(val * 0.70710678118f));
          scr[(i * 16 + g16 * 4 + r) * 68 + j * 16 + l16] = f2h(val);
        }
    }
    if (resid) {
      // fused residual: out(f32) += h2f(f2h(acc)) + rbias  (coalesced 16B ops)
#pragma unroll
      for (int rr = 0; rr < 8; ++rr) {
        const int lr = rr * 8 + (lane >> 3);
        const int lc = (lane & 7) * 8;
        const u16x8 val = *(const u16x8*)&scr[lr * 68 + lc];
        const int grow = row0 + wm * 128 + mh * 64 + lr;
        const int gcol = col0 + wn * 64 + lc;
        float* po = resid + (size_t)grow * N + gcol;
        const float4 b0 = ((const float4*)(rbias + gcol))[0];
        const float4 b1 = ((const float4*)(rbias + gcol))[1];
        float4 o0 = ((const float4*)po)[0];
        float4 o1 = ((const float4*)po)[1];
        o0.x += h2f(val[0]) + b0.x;
        o0.y += h2f(val[1]) + b0.y;
        o0.z += h2f(val[2]) + b0.z;
        o0.w += h2f(val[3]) + b0.w;
        o1.x += h2f(val[4]) + b1.x;
        o1.y += h2f(val[5]) + b1.y;
        o1.z += h2f(val[6]) + b1.z;
        o1.w += h2f(val[7]) + b1.w;
        ((float4*)po)[0] = o0;
        ((float4*)po)[1] = o1;
      }
    } else {
#pragma unroll
      for (int rr = 0; rr < 8; ++rr) {
        const int lr = rr * 8 + (lane >> 3);
        const int lc = (lane & 7) * 8;
        const u16x8 val = *(const u16x8*)&scr[lr * 68 + lc];
        *(u16x8*)(outB + (size_t)(row0 + wm * 128 + mh * 64 + lr) * N + col0 +
                  wn * 64 + lc) = val;
      }
    }
  }
}

// ---------------- attention stage 1: partial S = Q^T K over an n-chunk -------
__global__ __launch_bounds__(256) void attn_qk_part(
    const unsigned short* __restrict__ qkv, float* __restrict__ sp) {
  constexpr int ST = 72;
  __shared__ unsigned short sQT[64 * ST];  // [dd][n]
  __shared__ unsigned short sKT[64 * ST];  // [e][n]
  const int bx = blockIdx.x, bh = bx >> 2, chunk = bx & 3;
  const int b = bh >> 4, h = bh & 15;
  const size_t base = (size_t)b * 4096 * 3072 + (size_t)h * 64;
  const int tid = threadIdx.x, wave = tid >> 6, lane = tid & 63;
  const int l16 = lane & 15, g16 = lane >> 4;
  const int wm = wave & 1, wn = wave >> 1;
  const int srow = tid >> 2, sseg = tid & 3;

  f32x4 acc[2][2] = {};

  for (int ntl = 0; ntl < 16; ++ntl) {
    const int nt = chunk * 16 + ntl;
    __syncthreads();
    const size_t roff = base + (size_t)(nt * 64 + srow) * 3072 + sseg * 16;
    const u16x8 q0 = *(const u16x8*)(qkv + roff);
    const u16x8 q1 = *(const u16x8*)(qkv + roff + 8);
    const u16x8 k0 = *(const u16x8*)(qkv + roff + 1024);
    const u16x8 k1 = *(const u16x8*)(qkv + roff + 1032);
#pragma unroll
    for (int ii = 0; ii < 8; ++ii) {
      sQT[(sseg * 16 + ii) * ST + srow] = q0[ii];
      sQT[(sseg * 16 + 8 + ii) * ST + srow] = q1[ii];
      sKT[(sseg * 16 + ii) * ST + srow] = k0[ii];
      sKT[(sseg * 16 + 8 + ii) * ST + srow] = k1[ii];
    }
    __syncthreads();
#pragma unroll
    for (int kk = 0; kk < 2; ++kk) {
      f16x8 aq[2], bk[2];
#pragma unroll
      for (int i = 0; i < 2; ++i)
        aq[i] = __builtin_bit_cast(f16x8,
            *(const u16x8*)&sQT[(wm * 32 + i * 16 + l16) * ST + kk * 32 + g16 * 8]);
#pragma unroll
      for (int j = 0; j < 2; ++j)
        bk[j] = __builtin_bit_cast(f16x8,
            *(const u16x8*)&sKT[(wn * 32 + j * 16 + l16) * ST + kk * 32 + g16 * 8]);
#pragma unroll
      for (int i = 0; i < 2; ++i)
#pragma unroll
        for (int j = 0; j < 2; ++j)
          acc[i][j] = __builtin_amdgcn_mfma_f32_16x16x32_f16(aq[i], bk[j], acc[i][j], 0, 0, 0);
    }
  }

  float* o = sp + (size_t)bx * 4096;
#pragma unroll
  for (int i = 0; i < 2; ++i)
#pragma unroll
    for (int j = 0; j < 2; ++j)
#pragma unroll
      for (int r = 0; r < 4; ++r)
        o[(wm * 32 + i * 16 + g16 * 4 + r) * 64 + (wn * 32 + j * 16 + l16)] = acc[i][j][r];
}

// ---------------- attention stage 2: chunk-reduce + softmax -> Am (f16) ------
__global__ __launch_bounds__(256) void attn_softmax(
    const float* __restrict__ sp, unsigned short* __restrict__ am) {
  const int gid = blockIdx.x * 4 + (threadIdx.x >> 6);  // 0..8191
  const int lane = threadIdx.x & 63;
  const int bh = gid >> 6, dd = gid & 63;
  const float* p = sp + (size_t)bh * 16384 + dd * 64 + lane;
  const float v = p[0] + p[4096] + p[8192] + p[12288];
  float mx = v;
#pragma unroll
  for (int o = 32; o >= 1; o >>= 1) mx = fmaxf(mx, __shfl_xor(mx, o));
  const float e = __expf(0.125f * (v - mx));
  float s = e;
#pragma unroll
  for (int o = 32; o >= 1; o >>= 1) s += __shfl_xor(s, o);
  am[(size_t)bh * 4096 + dd * 64 + lane] = f2h(e / s);
}

// ---------------- attention stage 3: O = A * V over an n-chunk ---------------
// Output rows: o[b*4096 + dd*64 + h*4 + chunk][ntl*64 + local_col].
// Per-wave 32x32 tile is LDS-transposed so stores are ushort8 (16B) runs
// instead of 16 scalar 2B scattered stores (write-amplification fix).
__global__ __launch_bounds__(256) void attn_pv(
    const unsigned short* __restrict__ qkv, const unsigned short* __restrict__ am,
    unsigned short* __restrict__ o) {
  __shared__ unsigned short pvs[4 * 1088];  // per wave: 32 x 32, stride 34
  const int bx = blockIdx.x, bh = bx >> 2, chunk = bx & 3;
  const int b = bh >> 4, h = bh & 15;
  const size_t base = (size_t)b * 4096 * 3072 + (size_t)h * 64;
  const int tid = threadIdx.x, wave = tid >> 6, lane = tid & 63;
  const int l16 = lane & 15, g16 = lane >> 4;
  const int wm = wave & 1, wn = wave >> 1;
  unsigned short* tw = pvs + wave * 1088;

  f16x8 amf[2][2];
#pragma unroll
  for (int i = 0; i < 2; ++i)
#pragma unroll
    for (int kk = 0; kk < 2; ++kk)
      amf[i][kk] = __builtin_bit_cast(f16x8,
          *(const u16x8*)(am + (size_t)bh * 4096 +
                          (wm * 32 + i * 16 + l16) * 64 + kk * 32 + g16 * 8));

  for (int ntl = 0; ntl < 16; ++ntl) {
    const int nt = chunk * 16 + ntl;
    f32x4 oc[2][2] = {};
#pragma unroll
    for (int kk = 0; kk < 2; ++kk) {
#pragma unroll
      for (int j = 0; j < 2; ++j) {
        const f16x8 vf = __builtin_bit_cast(f16x8,
            *(const u16x8*)(qkv + base + 2048 +
                            (size_t)(nt * 64 + wn * 32 + j * 16 + l16) * 3072 +
                            kk * 32 + g16 * 8));
#pragma unroll
        for (int i = 0; i < 2; ++i)
          oc[i][j] = __builtin_amdgcn_mfma_f32_16x16x32_f16(amf[i][kk], vf, oc[i][j], 0, 0, 0);
      }
    }
    // wave-private LDS transpose (WAR vs prev-iter reads: drain first)
    asm volatile("s_waitcnt lgkmcnt(0)" ::: "memory");
#pragma unroll
    for (int i = 0; i < 2; ++i)
#pragma unroll
      for (int j = 0; j < 2; ++j)
#pragma unroll
        for (int r = 0; r < 4; ++r)
          tw[(i * 16 + g16 * 4 + r) * 34 + j * 16 + l16] = f2h(oc[i][j][r]);
    asm volatile("s_waitcnt lgkmcnt(0)" ::: "memory");
    const int rt = lane >> 1;            // 0..31: row within wave tile
    const int c0 = (lane & 1) * 16;      // 0 or 16
#pragma unroll
    for (int c2 = 0; c2 < 2; ++c2) {
      const int ct = c0 + c2 * 8;
      const u16x8 v8 = *(const u16x8*)&tw[rt * 34 + ct];
      const int row = b * 4096 + (wm * 32 + rt) * 64 + h * 4 + chunk;
      *(u16x8*)(o + (size_t)row * 1024 + ntl * 64 + wn * 32 + ct) = v8;
    }
  }
}

// -----------------------------------------------------------------------------
extern "C" void kernel_launch(void* const* d_in, const int* in_sizes, int n_in,
                              void* d_out, int out_size, void* d_ws, size_t ws_size,
                              hipStream_t stream) {
  (void)in_sizes; (void)n_in; (void)out_size; (void)ws_size;
  const float* x = (const float*)d_in[0];
  const float* ln1g = (const float*)d_in[1];
  const float* ln1b = (const float*)d_in[2];
  const float* ln2g = (const float*)d_in[3];
  const float* ln2b = (const float*)d_in[4];
  const float* wq = (const float*)d_in[5];
  const float* wk = (const float*)d_in[6];
  const float* wv = (const float*)d_in[7];
  const float* projw = (const float*)d_in[8];
  const float* projb = (const float*)d_in[9];
  const float* fc1w = (const float*)d_in[10];
  const float* fc1b = (const float*)d_in[11];
  const float* fc2w = (const float*)d_in[12];
  const float* fc2b = (const float*)d_in[13];
  float* out = (float*)d_out;

  const int M = 8 * 4096, C = 1024, HF = 2048;
  const size_t MC = (size_t)M * C;

  unsigned short* p = (unsigned short*)d_ws;
  unsigned short* wqkvT = p; p += (size_t)3 * C * C;  // [3072 x 1024]
  unsigned short* prT = p; p += (size_t)C * C;
  unsigned short* f1T = p; p += (size_t)HF * C;
  unsigned short* f2T = p; p += (size_t)C * HF;
  unsigned short* hb = p;  p += MC;          // region RA (64 MB)
  unsigned short* qkvb = p; p += 3 * MC;     // region RB (192 MB)
  // Aliases (lifetimes are strictly stream-ordered):
  float* Spart = (float*)hb;                 // attn scratch (8 MB), hb dead after qkv GEMM
  unsigned short* Am = wqkvT;                // 1 MB, wqkvT dead after qkv GEMM
  unsigned short* ob = hb;                   // attn output, clobbers consumed Spart
  unsigned short* projout = qkvb;            // RB[0,MC): qkvb dead after attn_pv
  unsigned short* h2 = qkvb + 2 * MC;        // RB[2MC,3MC)
  unsigned short* h3 = qkvb;                 // RB[0,2MC): projout dead after resid_ln
  unsigned short* yb = hb;                   // unused output slot for fused fc2

  TCArgs ta;
  ta.W[0] = wq;    ta.T[0] = wqkvT;                     ta.K[0] = C;  ta.N[0] = C;
  ta.W[1] = wk;    ta.T[1] = wqkvT + (size_t)C * C;     ta.K[1] = C;  ta.N[1] = C;
  ta.W[2] = wv;    ta.T[2] = wqkvT + (size_t)2 * C * C; ta.K[2] = C;  ta.N[2] = C;
  ta.W[3] = projw; ta.T[3] = prT;                       ta.K[3] = C;  ta.N[3] = C;
  ta.W[4] = fc1w;  ta.T[4] = f1T;                       ta.K[4] = C;  ta.N[4] = HF;
  ta.W[5] = fc2w;  ta.T[5] = f2T;                       ta.K[5] = HF; ta.N[5] = C;
  transpose_cast6<<<dim3(HF / 32, HF / 32, 6), 256, 0, stream>>>(ta);

  layernorm_cast<<<M, 256, 0, stream>>>(x, ln1g, ln1b, hb);

  gemm256<<<dim3(3 * C / 256, M / 256), 512, 0, stream>>>(
      hb, wqkvT, M, 3 * C, C, nullptr, qkvb, 0, nullptr, nullptr);

  attn_qk_part<<<512, 256, 0, stream>>>(qkvb, Spart);
  attn_softmax<<<2048, 256, 0, stream>>>(Spart, Am);
  attn_pv<<<512, 256, 0, stream>>>(qkvb, Am, ob);

  gemm256<<<dim3(C / 256, M / 256), 512, 0, stream>>>(
      ob, prT, M, C, C, nullptr, projout, 0, nullptr, nullptr);

  resid_ln<<<M, 256, 0, stream>>>(x, projout, projb, ln2g, ln2b, out, h2);

  gemm256<<<dim3(HF / 256, M / 256), 512, 0, stream>>>(
      h2, f1T, M, HF, C, fc1b, h3, 1, nullptr, nullptr);

  // fc2 with fused residual: out += h2f(f2h(acc)) + fc2b  (resid_add removed)
  gemm256<<<dim3(C / 256, M / 256), 512, 0, stream>>>(
      h3, f2T, M, C, HF, nullptr, yb, 0, out, fc2b);
}